// Round 4
// baseline (548.110 us; speedup 1.0000x reference)
//
#include <hip/hip_runtime.h>

// Fused 5x5 SAME conv + FastLIF + FastLI scan over T — FLOAT64 internal math.
// x: [T=256, 1, H=512, W=512] fp32, kernel: [1,1,5,5] fp32, out: [T,1,H,W] fp32.
//
// NUMERICS (identical to passing R3/R4/R6): conv accumulation + LIF/LI state
// in double, identical per-pixel FMA ordering, f32->f64 widening at LDS read
// (exact), output rounded to f32 at store, zero halo via never-overwritten
// zero registers. Expected absmax: exactly 0.03125.
//
// R7 RESTRUCTURE (R4 vs R6 post-mortem: halving LDS work left time pinned at
// ~2380 cyc/step -> neither LDS nor VALU pipe is binding; the per-step
// barrier lockstep x 25-deep f64 FMA dependence chain x 8 waves/CU is).
// Fix: WAVE-PRIVATE double-buffered halo tiles (each wave stages its own
// 6x68 halo for its 2 output rows) -> ZERO barriers in the whole kernel.
// Waves free-run and drift out of phase, mutually hiding LDS latency and
// FMA chain stalls. Row-overlap re-reads between waves are L2 hits (each
// x[t] plane is 1 MB). DS ops are in-order per wave -> wave-private LDS
// RAW/WAR is safe with the compiler's own counted waits; no sync needed.

namespace {

typedef float f32x2 __attribute__((ext_vector_type(2)));

constexpr int H = 512;
constexpr int W = 512;
constexpr int HW = H * W;
constexpr int TW = 64;                 // tile width (per block)
constexpr int TH = 8;                  // tile height (per block; 2 rows/wave)
constexpr int WAVE_ROWS = 2;           // output rows per wave
constexpr int WHALO_W = TW + 4;        // 68
constexpr int WHALO_H = WAVE_ROWS + 4; // 6
constexpr int WNLOAD = WHALO_W * WHALO_H;  // 408 floats per wave per timestep
constexpr int NSLOT = 7;               // ceil(408/64) staging slots per lane
constexpr int NTHREADS = 256;
constexpr int NWAVES = NTHREADS / 64;  // 4

__global__ __launch_bounds__(NTHREADS, 2)
void snn_fused(const float* __restrict__ x, const float* __restrict__ kern,
               float* __restrict__ out) {
    #pragma clang fp contract(off)

    // 4 waves x 2 buffers x 408 floats = 13056 B. Wave-private: no aliasing
    // across waves, hence no barriers anywhere in this kernel.
    __shared__ alignas(16) float smem[NWAVES][2][WNLOAD];

    const int tid  = threadIdx.x;
    const int lane = tid & 63;
    const int wv   = tid >> 6;                       // 0..3
    const int w0   = blockIdx.x * TW;
    const int h0   = blockIdx.y * TH + wv * WAVE_ROWS;  // wave's first out row

    // 5x5 weights, widened to f64 (exact). Wave-uniform.
    double wgt[25];
    #pragma unroll
    for (int i = 0; i < 25; ++i) wgt[i] = (double)kern[i];

    // Per-wave staging slots, precomputed once.
    int  goff[NSLOT];
    bool gval[NSLOT];
    #pragma unroll
    for (int i = 0; i < NSLOT; ++i) {
        int idx = lane + i * 64;
        int hr  = idx / WHALO_W;
        int hc  = idx - hr * WHALO_W;
        int gh  = h0 - 2 + hr;
        int gw  = w0 - 2 + hc;
        goff[i] = gh * W + gw;
        gval[i] = (idx < WNLOAD) &&
                  ((unsigned)gh < (unsigned)H) && ((unsigned)gw < (unsigned)W);
    }

    // One row, two adjacent (even-based) columns per thread, as in R6.
    const int lh  = lane >> 5;          // 0..1 within the wave
    const int lwp = (lane & 31) * 2;    // 0,2,..,62
    const int ghh = h0 + lh;
    const int gww = w0 + lwp;

    double s1a = 0.0, s2a = 0.0;   // col gww
    double s1b = 0.0, s2b = 0.0;   // col gww+1

    // Prefetch register sets; OOB slots stay 0 forever (zero halo).
    float rA[NSLOT], rB[NSLOT];
    #pragma unroll
    for (int i = 0; i < NSLOT; ++i) { rA[i] = 0.0f; rB[i] = 0.0f; }

    float* bufA = &smem[wv][0][0];
    float* bufB = &smem[wv][1][0];

    auto issue_loads = [&](int t, float* r) {
        const float* xt = x + (size_t)t * HW;
        #pragma unroll
        for (int i = 0; i < NSLOT; ++i) {
            if (gval[i]) r[i] = xt[goff[i]];
        }
    };

    auto stage_write = [&](float* buf, const float* r) {
        #pragma unroll
        for (int i = 0; i < NSLOT; ++i) {
            int idx = lane + i * 64;
            if (idx < WNLOAD) buf[idx] = r[i];
        }
    };

    // 5x5 conv (two adjacent cols, f64 FMA, per-pixel accumulation order
    // IDENTICAL to the verified R3/R4/R6 kernels) + LIF/LI + output store.
    auto step = [&](const float* buf, int t) {
        #pragma clang fp contract(off)
        const float* sm = buf + lh * WHALO_W + lwp;
        double acc0 = 0.0, acc1 = 0.0;
        #pragma unroll
        for (int kh = 0; kh < 5; ++kh) {
            const f32x2* r2 = reinterpret_cast<const f32x2*>(sm + kh * WHALO_W);
            f32x2 f0 = r2[0], f1 = r2[1], f2 = r2[2];
            double c0 = (double)f0.x, c1 = (double)f0.y;
            double c2 = (double)f1.x, c3 = (double)f1.y;
            double c4 = (double)f2.x, c5 = (double)f2.y;
            acc0 = __builtin_fma(wgt[kh * 5 + 0], c0, acc0);
            acc1 = __builtin_fma(wgt[kh * 5 + 0], c1, acc1);
            acc0 = __builtin_fma(wgt[kh * 5 + 1], c1, acc0);
            acc1 = __builtin_fma(wgt[kh * 5 + 1], c2, acc1);
            acc0 = __builtin_fma(wgt[kh * 5 + 2], c2, acc0);
            acc1 = __builtin_fma(wgt[kh * 5 + 2], c3, acc1);
            acc0 = __builtin_fma(wgt[kh * 5 + 3], c3, acc0);
            acc1 = __builtin_fma(wgt[kh * 5 + 3], c4, acc1);
            acc0 = __builtin_fma(wgt[kh * 5 + 4], c4, acc0);
            acc1 = __builtin_fma(wgt[kh * 5 + 4], c5, acc1);
        }

        {
            double v = 0.85 * s1a + acc0;
            double spk = (v >= 2.0) ? 1.0 : 0.0;
            s1a = v - spk * 2.0;
            s2a = 0.9 * s2a + spk;
        }
        {
            double v = 0.85 * s1b + acc1;
            double spk = (v >= 2.0) ? 1.0 : 0.0;
            s1b = v - spk * 2.0;
            s2b = 0.9 * s2b + spk;
        }

        f32x2 o;
        o.x = (float)s2a;
        o.y = (float)s2b;
        f32x2* outp = reinterpret_cast<f32x2*>(
            out + (size_t)t * HW + (size_t)ghh * W + gww);
        __builtin_nontemporal_store(o, outp);
    };

    // ---- prologue: bufA <- x[0]; x[1] left in flight in rB.
    issue_loads(0, rA);
    issue_loads(1, rB);
    stage_write(bufA, rA);

    // ---- steady state: 2 timesteps per iteration, no barriers.
    // Invariant entering iter tb (t0 = 2*tb): bufA holds x[t0] (own wave),
    // rB holds x[t0+1] (in flight or arrived).
    for (int tb = 0; tb < 127; ++tb) {
        const int t0 = 2 * tb;

        issue_loads(t0 + 2, rA);        // ~1 step of latency slack
        step(bufA, t0);
        stage_write(bufB, rB);          // bufB <- x[t0+1]

        issue_loads(t0 + 3, rB);
        step(bufB, t0 + 1);
        stage_write(bufA, rA);          // bufA <- x[t0+2]
    }

    // ---- tail: t = 254, 255 (no further prefetch)
    step(bufA, 254);
    stage_write(bufB, rB);              // bufB <- x[255]
    step(bufB, 255);
}

}  // namespace

extern "C" void kernel_launch(void* const* d_in, const int* in_sizes, int n_in,
                              void* d_out, int out_size, void* d_ws, size_t ws_size,
                              hipStream_t stream) {
    const float* x    = (const float*)d_in[0];
    const float* kern = (const float*)d_in[1];
    float* out        = (float*)d_out;

    dim3 grid(W / TW, H / TH);  // (8, 64) = 512 blocks -> 2 blocks/CU
    snn_fused<<<grid, dim3(NTHREADS), 0, stream>>>(x, kern, out);
}

// Round 5
// 538.617 us; speedup vs baseline: 1.0176x; 1.0176x over previous
//
#include <hip/hip_runtime.h>

// Fused 5x5 SAME conv + FastLIF + FastLI scan over T — FLOAT64 internal math.
// x: [T=256, 1, H=512, W=512] fp32, kernel: [1,1,5,5] fp32, out: [T,1,H,W] fp32.
//
// NUMERICS (identical to passing R3/R4/R6/R7): conv accumulation + LIF/LI
// state in double, identical per-pixel FMA ordering (kh 0..4, kw 0..4, one
// f64 accumulator), f32->f64 widening at LDS read (exact), output rounded to
// f32 at store, zero halo via never-overwritten zero registers.
// Expected absmax: exactly 0.03125.
//
// R8 (latency-bound at 2 waves/SIMD per R4/R6/R7 triangulation: LDS-bytes
// halved (R6) and barrier-free (R7) both left time pinned at ~2380 cyc/step
// with every pipe at 35-50%): the only remaining lever is WAVE COUNT.
// 1 px/thread doubles total waves: 4096 waves -> 16 waves/CU -> 4/SIMD,
// halving per-wave work and doubling latency-hiding. TH=4 tiles give 4
// independently-drifting blocks per CU (per-block barriers don't re-lockstep
// the CU). Per-px LDS reads rise to 5x5 floats (read as 4B-aligned pairs ->
// ds_read2_b32), which R7's FETCH data says L2 absorbs on the global side.
//   - R4/R6 pipeline kept: register-staged prefetch 2 steps ahead,
//     no-vmcnt-drain barrier, t-loop unrolled by 2, static buffers/registers.

namespace {

// 8-byte LDS read with only 4B alignment guarantee -> backend emits
// ds_read2_b32 (arbitrary-parity column base, no shifted copies needed).
struct __attribute__((packed, aligned(4))) fpair { float a, b; };

constexpr int H = 512;
constexpr int W = 512;
constexpr int HW = H * W;
constexpr int TW = 64;                 // tile width
constexpr int TH = 4;                  // tile height (1 row x 1 col per thread)
constexpr int HALO_W = TW + 4;         // 68
constexpr int HALO_H = TH + 4;         // 8
constexpr int NLOAD = HALO_W * HALO_H; // 544 floats per tile per timestep
constexpr int NTHREADS = 256;
constexpr int NSLOT = 3;               // ceil(544/256) staging slots

__device__ __forceinline__ void sync_nodrain_vm() {
    // __syncthreads() drains vmcnt(0) and kills the global prefetch pipeline.
    // We only need LDS visibility: drain lgkm, barrier, sched fences.
    __builtin_amdgcn_sched_barrier(0);
    asm volatile("s_waitcnt lgkmcnt(0)");
    __builtin_amdgcn_s_barrier();
    __builtin_amdgcn_sched_barrier(0);
}

__global__ __launch_bounds__(NTHREADS, 4)
void snn_fused(const float* __restrict__ x, const float* __restrict__ kern,
               float* __restrict__ out) {
    #pragma clang fp contract(off)

    __shared__ alignas(16) float smem[2][NLOAD];   // 2 x 544 x 4B = 4352 B

    const int tid = threadIdx.x;
    const int w0 = blockIdx.x * TW;
    const int h0 = blockIdx.y * TH;

    // 5x5 weights, widened to f64 (exact). Wave-uniform.
    double wgt[25];
    #pragma unroll
    for (int i = 0; i < 25; ++i) wgt[i] = (double)kern[i];

    // Staging slots precomputed once; only the x base pointer moves per step.
    int  goff[NSLOT];
    bool gval[NSLOT];
    #pragma unroll
    for (int i = 0; i < NSLOT; ++i) {
        int idx = tid + i * NTHREADS;
        int lhh = idx / HALO_W;
        int lww = idx - lhh * HALO_W;
        int gh = h0 - 2 + lhh;
        int gw = w0 - 2 + lww;
        goff[i] = gh * W + gw;
        gval[i] = (idx < NLOAD) &&
                  ((unsigned)gh < (unsigned)H) && ((unsigned)gw < (unsigned)W);
    }

    // One pixel per thread.
    const int lw = tid & 63;            // 0..63
    const int lh = tid >> 6;            // 0..3
    const int gh = h0 + lh;
    const int gw = w0 + lw;

    double s1 = 0.0, s2 = 0.0;

    // Prefetch register sets; OOB slots stay 0 forever (zero halo).
    float rA[NSLOT], rB[NSLOT];
    #pragma unroll
    for (int i = 0; i < NSLOT; ++i) { rA[i] = 0.0f; rB[i] = 0.0f; }

    auto issue_loads = [&](int t, float* r) {
        const float* xt = x + (size_t)t * HW;
        #pragma unroll
        for (int i = 0; i < NSLOT; ++i) {
            if (gval[i]) r[i] = xt[goff[i]];
        }
    };

    auto stage_write = [&](float* buf, const float* r) {
        #pragma unroll
        for (int i = 0; i < NSLOT; ++i) {
            int idx = tid + i * NTHREADS;
            if (idx < NLOAD) buf[idx] = r[i];
        }
    };

    // 5x5 conv (one px, f64 FMA, per-pixel accumulation order IDENTICAL to
    // the verified kernels) + LIF/LI + output store.
    auto step = [&](const float* buf, int t) {
        #pragma clang fp contract(off)
        // Output px (lh,lw) needs halo rows lh..lh+4, halo cols lw..lw+4.
        const float* sm = buf + lh * HALO_W + lw;
        double acc = 0.0;
        #pragma unroll
        for (int kh = 0; kh < 5; ++kh) {
            const float* row = sm + kh * HALO_W;
            // 4B-aligned pair loads -> ds_read2_b32; last element scalar.
            fpair p01 = *reinterpret_cast<const fpair*>(row);
            fpair p23 = *reinterpret_cast<const fpair*>(row + 2);
            float c4f = row[4];
            double c0 = (double)p01.a, c1 = (double)p01.b;
            double c2 = (double)p23.a, c3 = (double)p23.b;
            double c4 = (double)c4f;
            acc = __builtin_fma(wgt[kh * 5 + 0], c0, acc);
            acc = __builtin_fma(wgt[kh * 5 + 1], c1, acc);
            acc = __builtin_fma(wgt[kh * 5 + 2], c2, acc);
            acc = __builtin_fma(wgt[kh * 5 + 3], c3, acc);
            acc = __builtin_fma(wgt[kh * 5 + 4], c4, acc);
        }

        double v = 0.85 * s1 + acc;
        double spk = (v >= 2.0) ? 1.0 : 0.0;
        s1 = v - spk * 2.0;
        s2 = 0.9 * s2 + spk;

        float* outp = out + (size_t)t * HW + (size_t)gh * W + gw;
        __builtin_nontemporal_store((float)s2, outp);
    };

    // ---- pipeline prologue: buf0 <- x[0]; x[1] left in flight in rB.
    issue_loads(0, rA);
    issue_loads(1, rB);
    stage_write(smem[0], rA);
    sync_nodrain_vm();

    // ---- steady state: 2 timesteps per iteration.
    // Invariant entering iter tb (t0 = 2*tb): smem[0] holds x[t0] (all waves,
    // barrier'd), rB holds x[t0+1] (in flight or arrived).
    for (int tb = 0; tb < 127; ++tb) {
        const int t0 = 2 * tb;

        issue_loads(t0 + 2, rA);        // ~1.5 iterations of latency slack
        step(smem[0], t0);
        stage_write(smem[1], rB);       // rB = x[t0+1]
        sync_nodrain_vm();

        issue_loads(t0 + 3, rB);
        step(smem[1], t0 + 1);
        stage_write(smem[0], rA);       // rA = x[t0+2]
        sync_nodrain_vm();
    }

    // ---- tail: t = 254, 255 (no further prefetch)
    step(smem[0], 254);
    stage_write(smem[1], rB);           // rB = x[255]
    sync_nodrain_vm();
    step(smem[1], 255);
}

}  // namespace

extern "C" void kernel_launch(void* const* d_in, const int* in_sizes, int n_in,
                              void* d_out, int out_size, void* d_ws, size_t ws_size,
                              hipStream_t stream) {
    const float* x    = (const float*)d_in[0];
    const float* kern = (const float*)d_in[1];
    float* out        = (float*)d_out;

    dim3 grid(W / TW, H / TH);  // (8, 128) = 1024 blocks -> 4 blocks/CU
    snn_fused<<<grid, dim3(NTHREADS), 0, stream>>>(x, kern, out);
}